// Round 1
// baseline (37.533 us; speedup 1.0000x reference)
//
#include <hip/hip_runtime.h>

#define BB 16384
#define AA 512

// One block per sample (row). 256 threads x 2 annotations = 512 annotations.
extern "C" __global__ void __launch_bounds__(256)
mtl_partial(const float* __restrict__ preds, const int* __restrict__ labels,
            const float* __restrict__ weights, float* __restrict__ part,
            int* __restrict__ valid) {
    const int b   = blockIdx.x;
    const int tid = threadIdx.x;
    const int a0  = tid * 2;

    const float4 p = *reinterpret_cast<const float4*>(preds + ((size_t)b * AA + a0) * 2);
    const int2   l = *reinterpret_cast<const int2*>(labels + (size_t)b * AA + a0);
    const float2 w = *reinterpret_cast<const float2*>(weights + a0);

    float sum = 0.0f;
    int   cnt = 0;

    // annotation a0 (preds p.x = class0, p.y = class1)
    {
        const int   lab = l.x;
        const float p0 = p.x, p1 = p.y;
        const float m0 = fmaxf(p0, 0.0f);
        const float e0 = __logf(1.0f + __expf(-fabsf(p0)));
        const float m1 = fmaxf(p1, 0.0f);
        const float e1 = __logf(1.0f + __expf(-fabsf(p1)));
        const float sp_p0 = m0 + e0;            // softplus(p0)
        const float sp_n0 = (m0 - p0) + e0;     // softplus(-p0)
        const float sp_p1 = m1 + e1;
        const float sp_n1 = (m1 - p1) + e1;
        // t=1 (lab==1): 0.5*(softplus(p0) + w*softplus(-p1))
        // t=0 (lab==0 or -1): 0.5*(w*softplus(-p0) + softplus(p1))
        const float pa = (lab == 1) ? 0.5f * (sp_p0 + w.x * sp_n1)
                                    : 0.5f * (w.x * sp_n0 + sp_p1);
        const bool valid_ann = (lab != -1);
        sum += valid_ann ? pa : 0.0f;
        cnt += valid_ann ? 1 : 0;
    }
    // annotation a0+1 (preds p.z = class0, p.w = class1)
    {
        const int   lab = l.y;
        const float p0 = p.z, p1 = p.w;
        const float m0 = fmaxf(p0, 0.0f);
        const float e0 = __logf(1.0f + __expf(-fabsf(p0)));
        const float m1 = fmaxf(p1, 0.0f);
        const float e1 = __logf(1.0f + __expf(-fabsf(p1)));
        const float sp_p0 = m0 + e0;
        const float sp_n0 = (m0 - p0) + e0;
        const float sp_p1 = m1 + e1;
        const float sp_n1 = (m1 - p1) + e1;
        const float pa = (lab == 1) ? 0.5f * (sp_p0 + w.y * sp_n1)
                                    : 0.5f * (w.y * sp_n0 + sp_p1);
        const bool valid_ann = (lab != -1);
        sum += valid_ann ? pa : 0.0f;
        cnt += valid_ann ? 1 : 0;
    }

    // wave (64-lane) reduction
    #pragma unroll
    for (int off = 32; off > 0; off >>= 1) {
        sum += __shfl_down(sum, off);
        cnt += __shfl_down(cnt, off);
    }

    __shared__ float sl[4];
    __shared__ int   cl[4];
    const int wave = tid >> 6;
    const int lane = tid & 63;
    if (lane == 0) { sl[wave] = sum; cl[wave] = cnt; }
    __syncthreads();
    if (tid == 0) {
        const float S = sl[0] + sl[1] + sl[2] + sl[3];
        const int   C = cl[0] + cl[1] + cl[2] + cl[3];
        part[b]  = (C > 0) ? S : 0.0f;   // where(has_valid, per_sample, 0)
        valid[b] = (C > 0) ? 1 : 0;      // has_valid
    }
}

// Deterministic final reduction: one block sums the 16384 partials.
extern "C" __global__ void __launch_bounds__(256)
mtl_final(const float* __restrict__ part, const int* __restrict__ valid,
          float* __restrict__ out) {
    const int tid = threadIdx.x;
    float s = 0.0f;
    int   c = 0;
    for (int i = tid; i < BB; i += 256) {
        s += part[i];
        c += valid[i];
    }
    #pragma unroll
    for (int off = 32; off > 0; off >>= 1) {
        s += __shfl_down(s, off);
        c += __shfl_down(c, off);
    }
    __shared__ float sl[4];
    __shared__ int   cl[4];
    const int wave = tid >> 6;
    const int lane = tid & 63;
    if (lane == 0) { sl[wave] = s; cl[wave] = c; }
    __syncthreads();
    if (tid == 0) {
        const float S = sl[0] + sl[1] + sl[2] + sl[3];
        const int   C = cl[0] + cl[1] + cl[2] + cl[3];
        out[0] = S / fmaxf((float)C, 1.0f);   // sum / max(n_valid, 1)
    }
}

extern "C" void kernel_launch(void* const* d_in, const int* in_sizes, int n_in,
                              void* d_out, int out_size, void* d_ws, size_t ws_size,
                              hipStream_t stream) {
    const float* preds   = (const float*)d_in[0];
    const int*   labels  = (const int*)d_in[1];
    const float* weights = (const float*)d_in[2];
    float*       out     = (float*)d_out;

    float* part  = (float*)d_ws;
    int*   valid = (int*)((char*)d_ws + (size_t)BB * sizeof(float));

    mtl_partial<<<BB, 256, 0, stream>>>(preds, labels, weights, part, valid);
    mtl_final<<<1, 256, 0, stream>>>(part, valid, out);
}

// Round 2
// 26.968 us; speedup vs baseline: 1.3918x; 1.3918x over previous
//
#include <hip/hip_runtime.h>

#define BB 16384
#define AA 512
#define ROWS_PER_BLOCK 4   // 4 waves per 256-thread block, one row per wave

// One 64-lane wave per sample row; each lane handles 4 float4 chunks
// (= 8 annotations), perfectly coalesced. No LDS, no __syncthreads.
extern "C" __global__ void __launch_bounds__(256)
mtl_partial(const float* __restrict__ preds, const int* __restrict__ labels,
            const float* __restrict__ weights, float2* __restrict__ part) {
    const int tid  = threadIdx.x;
    const int wv   = tid >> 6;
    const int lane = tid & 63;
    const int row  = blockIdx.x * ROWS_PER_BLOCK + wv;

    const float* prow = preds  + (size_t)row * (AA * 2);
    const int*   lrow = labels + (size_t)row * AA;

    float sum  = 0.0f;
    bool  anyv = false;

    #pragma unroll
    for (int k = 0; k < 4; ++k) {
        const int c = lane + (k << 6);   // float4-chunk index within row, 0..255
        const float4 p = *reinterpret_cast<const float4*>(prow + (size_t)c * 4);
        const int2   l = *reinterpret_cast<const int2*>(lrow + (size_t)c * 2);
        const float2 w = *reinterpret_cast<const float2*>(weights + (size_t)c * 2);

        // annotation 2c: (p.x = class0, p.y = class1), label l.x, weight w.x
        {
            const float p0 = p.x, p1 = p.y;
            const float m0 = fmaxf(p0, 0.0f);
            const float e0 = __logf(1.0f + __expf(-fabsf(p0)));
            const float m1 = fmaxf(p1, 0.0f);
            const float e1 = __logf(1.0f + __expf(-fabsf(p1)));
            // t=1: 0.5*(softplus(p0) + w*softplus(-p1))
            // t=0: 0.5*(w*softplus(-p0) + softplus(p1))
            const float pa = (l.x == 1)
                ? 0.5f * ((m0 + e0) + w.x * ((m1 - p1) + e1))
                : 0.5f * (w.x * ((m0 - p0) + e0) + (m1 + e1));
            const bool v = (l.x != -1);
            sum += v ? pa : 0.0f;
            anyv |= v;
        }
        // annotation 2c+1: (p.z, p.w), label l.y, weight w.y
        {
            const float p0 = p.z, p1 = p.w;
            const float m0 = fmaxf(p0, 0.0f);
            const float e0 = __logf(1.0f + __expf(-fabsf(p0)));
            const float m1 = fmaxf(p1, 0.0f);
            const float e1 = __logf(1.0f + __expf(-fabsf(p1)));
            const float pa = (l.y == 1)
                ? 0.5f * ((m0 + e0) + w.y * ((m1 - p1) + e1))
                : 0.5f * (w.y * ((m0 - p0) + e0) + (m1 + e1));
            const bool v = (l.y != -1);
            sum += v ? pa : 0.0f;
            anyv |= v;
        }
    }

    // A row with zero valid annotations contributes exactly 0 to the sum,
    // so no where() needed — only has_valid for the denominator.
    #pragma unroll
    for (int off = 32; off > 0; off >>= 1) sum += __shfl_down(sum, off);
    const bool has = (__ballot(anyv) != 0ULL);
    if (lane == 0) part[row] = make_float2(sum, has ? 1.0f : 0.0f);
}

// Deterministic final reduction over 16384 float2 partials.
extern "C" __global__ void __launch_bounds__(1024)
mtl_final(const float2* __restrict__ part, float* __restrict__ out) {
    const int tid = threadIdx.x;
    float s = 0.0f, c = 0.0f;
    for (int i = tid; i < BB; i += 1024) {
        const float2 v = part[i];
        s += v.x;
        c += v.y;
    }
    #pragma unroll
    for (int off = 32; off > 0; off >>= 1) {
        s += __shfl_down(s, off);
        c += __shfl_down(c, off);
    }
    __shared__ float sl[16];
    __shared__ float cl[16];
    const int wave = tid >> 6;
    const int lane = tid & 63;
    if (lane == 0) { sl[wave] = s; cl[wave] = c; }
    __syncthreads();
    if (tid == 0) {
        float S = 0.0f, C = 0.0f;
        #pragma unroll
        for (int i = 0; i < 16; ++i) { S += sl[i]; C += cl[i]; }
        out[0] = S / fmaxf(C, 1.0f);
    }
}

extern "C" void kernel_launch(void* const* d_in, const int* in_sizes, int n_in,
                              void* d_out, int out_size, void* d_ws, size_t ws_size,
                              hipStream_t stream) {
    const float* preds   = (const float*)d_in[0];
    const int*   labels  = (const int*)d_in[1];
    const float* weights = (const float*)d_in[2];
    float*       out     = (float*)d_out;

    float2* part = (float2*)d_ws;   // 16384 * 8 B = 128 KiB

    mtl_partial<<<BB / ROWS_PER_BLOCK, 256, 0, stream>>>(preds, labels, weights, part);
    mtl_final<<<1, 1024, 0, stream>>>(part, out);
}

// Round 3
// 23.698 us; speedup vs baseline: 1.5838x; 1.1380x over previous
//
#include <hip/hip_runtime.h>

#define BB 16384
#define AA 512
#define NBLK 2048            // 8 blocks/CU * 256 CU: fully resident
#define ROWS_PER_WAVE 2      // 16384 rows / (2048 blocks * 4 waves)

// One 64-lane wave per 2 consecutive rows; lane handles 4 float4 chunks
// (= 8 annotations) per row, coalesced. Single shfl-reduce chain per wave.
extern "C" __global__ void __launch_bounds__(256, 8)
mtl_partial(const float* __restrict__ preds, const int* __restrict__ labels,
            const float* __restrict__ weights, float2* __restrict__ part) {
    const int tid  = threadIdx.x;
    const int wv   = tid >> 6;
    const int lane = tid & 63;
    const int gw   = blockIdx.x * 4 + wv;          // global wave id, 0..8191
    const int row0 = gw * ROWS_PER_WAVE;

    float sum = 0.0f;
    float cnt = 0.0f;

    for (int r = 0; r < ROWS_PER_WAVE; ++r) {
        const int row = row0 + r;
        const float* prow = preds  + (size_t)row * (AA * 2);
        const int*   lrow = labels + (size_t)row * AA;

        bool anyv = false;
        #pragma unroll
        for (int k = 0; k < 4; ++k) {
            const int c = lane + (k << 6);         // float4-chunk 0..255
            const float4 p = *reinterpret_cast<const float4*>(prow + (size_t)c * 4);
            const int2   l = *reinterpret_cast<const int2*>(lrow + (size_t)c * 2);
            const float2 w = *reinterpret_cast<const float2*>(weights + (size_t)c * 2);

            // annotation 2c: preds (p.x,p.y), label l.x, weight w.x
            {
                const float p0 = p.x, p1 = p.y;
                const float m0 = fmaxf(p0, 0.0f);
                const float e0 = __logf(1.0f + __expf(-fabsf(p0)));
                const float m1 = fmaxf(p1, 0.0f);
                const float e1 = __logf(1.0f + __expf(-fabsf(p1)));
                // t=1: 0.5*(softplus(p0) + w*softplus(-p1))
                // t=0: 0.5*(w*softplus(-p0) + softplus(p1))
                const float pa = (l.x == 1)
                    ? 0.5f * ((m0 + e0) + w.x * ((m1 - p1) + e1))
                    : 0.5f * (w.x * ((m0 - p0) + e0) + (m1 + e1));
                const bool v = (l.x != -1);
                sum += v ? pa : 0.0f;
                anyv |= v;
            }
            // annotation 2c+1: preds (p.z,p.w), label l.y, weight w.y
            {
                const float p0 = p.z, p1 = p.w;
                const float m0 = fmaxf(p0, 0.0f);
                const float e0 = __logf(1.0f + __expf(-fabsf(p0)));
                const float m1 = fmaxf(p1, 0.0f);
                const float e1 = __logf(1.0f + __expf(-fabsf(p1)));
                const float pa = (l.y == 1)
                    ? 0.5f * ((m0 + e0) + w.y * ((m1 - p1) + e1))
                    : 0.5f * (w.y * ((m0 - p0) + e0) + (m1 + e1));
                const bool v = (l.y != -1);
                sum += v ? pa : 0.0f;
                anyv |= v;
            }
        }
        // per-row has_valid; all-invalid rows contribute 0 to sum anyway
        cnt += (__ballot(anyv) != 0ULL) ? 1.0f : 0.0f;
    }

    #pragma unroll
    for (int off = 32; off > 0; off >>= 1) sum += __shfl_down(sum, off);
    // cnt is wave-uniform (ballot result), no reduction needed

    __shared__ float2 sl[4];
    if (lane == 0) sl[wv] = make_float2(sum, cnt);
    __syncthreads();
    if (tid == 0) {
        float2 a = sl[0], b = sl[1], c = sl[2], d = sl[3];
        part[blockIdx.x] = make_float2(a.x + b.x + c.x + d.x,
                                       a.y + b.y + c.y + d.y);
    }
}

// Single-wave final reduction over 2048 float2 (16 KiB).
extern "C" __global__ void __launch_bounds__(64)
mtl_final(const float2* __restrict__ part, float* __restrict__ out) {
    const int lane = threadIdx.x;
    const float4* p4 = reinterpret_cast<const float4*>(part);  // 1024 float4
    float s = 0.0f, c = 0.0f;
    #pragma unroll
    for (int k = 0; k < 16; ++k) {
        const float4 v = p4[lane + (k << 6)];
        s += v.x + v.z;
        c += v.y + v.w;
    }
    #pragma unroll
    for (int off = 32; off > 0; off >>= 1) {
        s += __shfl_down(s, off);
        c += __shfl_down(c, off);
    }
    if (lane == 0) out[0] = s / fmaxf(c, 1.0f);
}

extern "C" void kernel_launch(void* const* d_in, const int* in_sizes, int n_in,
                              void* d_out, int out_size, void* d_ws, size_t ws_size,
                              hipStream_t stream) {
    const float* preds   = (const float*)d_in[0];
    const int*   labels  = (const int*)d_in[1];
    const float* weights = (const float*)d_in[2];
    float*       out     = (float*)d_out;

    float2* part = (float2*)d_ws;   // 2048 * 8 B = 16 KiB

    mtl_partial<<<NBLK, 256, 0, stream>>>(preds, labels, weights, part);
    mtl_final<<<1, 64, 0, stream>>>(part, out);
}